// Round 7
// baseline (216.487 us; speedup 1.0000x reference)
//
#include <hip/hip_runtime.h>
#include <hip/hip_bf16.h>
#include <math.h>

// VOCAB=50000, EMBED=256, MAXLEN=512, UNITS=32, F1=16, BATCH=512.
#define TT 512
#define BB 512
#define EE 256
#define UU 32
#define FF1 16

__device__ __forceinline__ void fma4(float4& a, float s, const float4& v) {
    a.x = fmaf(s, v.x, a.x); a.y = fmaf(s, v.y, a.y);
    a.z = fmaf(s, v.z, a.z); a.w = fmaf(s, v.w, a.w);
}

// tanh(x) = 1 - 2/(e^{2x}+1), branch-free (exp2+rcp HW approx).
__device__ __forceinline__ float fast_tanh(float x) {
    float e = __builtin_amdgcn_exp2f(x * 2.8853900817779268f);  // e^{2x}
    float r = __builtin_amdgcn_rcpf(e + 1.0f);
    return fmaf(-2.0f, r, 1.0f);
}

__device__ __forceinline__ float rdlane(float v, int lane) {
    return __int_as_float(__builtin_amdgcn_readlane(__float_as_int(v), lane));
}

// pull value from lane (addr_bytes>>2) across the full 64-lane wave
__device__ __forceinline__ float bperm(int addr_bytes, float v) {
    return __int_as_float(
        __builtin_amdgcn_ds_bpermute(addr_bytes, __float_as_int(v)));
}

// ---------------------------------------------------------------------------
// Kernel A: P[r][u] = emb[r] @ Wx[:,u] + bias[u] — register-tiled GEMV.
// 16 rows/wave (2 rows/lane): 3125 waves ~ 12/CU (3/SIMD) so the A/B
// ping-pong prefetch plus TLP covers ~900-cyc HBM latency (round-6's
// 32-row version had only 1.5 waves/SIMD -> uncovered stalls, ~70 us).
// lane = rg*8+ug: rg(0..7) picks a 2-row group, ug(0..7) a 4-unit quad.
// ---------------------------------------------------------------------------
__global__ __launch_bounds__(64) void proj_gemv(
    const float* __restrict__ emb, const float* __restrict__ Wx,
    const float* __restrict__ bias, float* __restrict__ P, int nrows)
{
    const int lane = threadIdx.x;
    const int ug = lane & 7;
    const int rg = lane >> 3;
    const int r0 = blockIdx.x * 16 + rg * 2;     // rows r0, r0+1 (exact fit)

    const float4* xp0 = (const float4*)(emb + (size_t)r0 * EE);
    const float4* xp1 = (const float4*)(emb + (size_t)(r0 + 1) * EE);
    const float4* wxp = (const float4*)Wx + ug;  // row k -> wxp[k*8]

    float4 acc0 = make_float4(0.f, 0.f, 0.f, 0.f);
    float4 acc1 = make_float4(0.f, 0.f, 0.f, 0.f);

    float4 xA0, xA1, xB0, xB1, wA[4], wB[4];
    xA0 = xp0[0]; xA1 = xp1[0];
    #pragma unroll
    for (int kk = 0; kk < 4; ++kk) wA[kk] = wxp[kk * 8];

    for (int k4 = 0; k4 < 64; k4 += 2) {
        // prefetch odd iter (k4+1)
        xB0 = xp0[k4 + 1]; xB1 = xp1[k4 + 1];
        #pragma unroll
        for (int kk = 0; kk < 4; ++kk) wB[kk] = wxp[(4 * (k4 + 1) + kk) * 8];
        // compute even iter
        fma4(acc0, xA0.x, wA[0]); fma4(acc0, xA0.y, wA[1]);
        fma4(acc0, xA0.z, wA[2]); fma4(acc0, xA0.w, wA[3]);
        fma4(acc1, xA1.x, wA[0]); fma4(acc1, xA1.y, wA[1]);
        fma4(acc1, xA1.z, wA[2]); fma4(acc1, xA1.w, wA[3]);
        // prefetch next even iter (wraps on last pass — harmless)
        const int kn = (k4 + 2) & 63;
        xA0 = xp0[kn]; xA1 = xp1[kn];
        #pragma unroll
        for (int kk = 0; kk < 4; ++kk) wA[kk] = wxp[(4 * kn + kk) * 8];
        // compute odd iter
        fma4(acc0, xB0.x, wB[0]); fma4(acc0, xB0.y, wB[1]);
        fma4(acc0, xB0.z, wB[2]); fma4(acc0, xB0.w, wB[3]);
        fma4(acc1, xB1.x, wB[0]); fma4(acc1, xB1.y, wB[1]);
        fma4(acc1, xB1.z, wB[2]); fma4(acc1, xB1.w, wB[3]);
    }

    const float4 bq = ((const float4*)bias)[ug];
    acc0.x += bq.x; acc0.y += bq.y; acc0.z += bq.z; acc0.w += bq.w;
    acc1.x += bq.x; acc1.y += bq.y; acc1.z += bq.z; acc1.w += bq.w;
    *((float4*)(P + (size_t)r0 * UU) + ug)       = acc0;
    *((float4*)(P + (size_t)(r0 + 1) * UU) + ug) = acc1;
}

// ---------------------------------------------------------------------------
// Kernel B: h_t = tanh(x_t + h_{t-1} @ Wh); fused heads + sigmoid.
// One batch row per 64-lane wave; x-stream (64 KB) staged in LDS upfront
// via gathered global_load_lds width=16 (round-6 structure, it won).
// NEW: k-SPLIT across wave halves — lane u sums k=0..15, lane u+32 sums
// k=16..31 (16 FMAs each, half the chain depth); h broadcast via
// ds_bpermute (VGPR-only: no VALU->SGPR hazards; LDS pipe is idle at
// 2 waves/CU); one xor-32 bpermute combines the halves. x is added AFTER
// the combine (both halves read the same xs value), so z — and h — stay
// replicated in both halves.
// ---------------------------------------------------------------------------
__global__ __launch_bounds__(64) void scan_heads(
    const int* __restrict__ tokens, const float* __restrict__ P,
    const float* __restrict__ Wh,
    const float* __restrict__ W1, const float* __restrict__ b1,
    const float* __restrict__ W2, const float* __restrict__ b2,
    float* __restrict__ out)
{
    __shared__ float xs[TT * UU];      // 512 rows x 128 B = 64 KB

    const int L = threadIdx.x;
    const int u = L & 31;
    const int hi = L >> 5;             // 0: k=0..15, 1: k=16..31
    const int b = blockIdx.x;
    const int* trow = tokens + b * TT;

    // this half-lane's 16 Wh rows: wh[j] = Wh[hi*16 + j][u]
    float wh[16];
    #pragma unroll
    for (int j = 0; j < 16; ++j) wh[j] = Wh[(hi * 16 + j) * UU + u];

    const int pbase = hi * 64;         // bpermute byte-addr base (k0*4)
    const int xaddr = (L ^ 32) * 4;    // cross-half partner

    // ---- gather phase: 64 global_load_lds instrs, 8 tokens each ----
    const int sub = L >> 3;            // token-within-group
    const int q   = L & 7;             // 16-B chunk within the 128-B row
    for (int c = 0; c < 8; ++c) {
        int tk8[8];
        #pragma unroll
        for (int i = 0; i < 8; ++i)
            tk8[i] = trow[c * 64 + i * 8 + sub];
        #pragma unroll
        for (int i = 0; i < 8; ++i) {
            const float* src = P + (size_t)tk8[i] * UU + q * 4;
            float* dst = xs + (c * 64 + i * 8) * UU;    // wave-uniform base
            __builtin_amdgcn_global_load_lds(
                (const __attribute__((address_space(1))) void*)src,
                (__attribute__((address_space(3))) void*)dst, 16, 0, 0);
        }
    }
    __syncthreads();   // drains vmcnt: all LDS rows resident

    // ---- scan: pure LDS-pipe + VALU ----
    float xr[4];
    #pragma unroll
    for (int j = 0; j < 4; ++j) xr[j] = xs[j * UU + u];

    float h = 0.f;                     // h[u], replicated in both halves

    for (int t = 0; t < TT; t += 4) {
        #pragma unroll
        for (int j = 0; j < 4; ++j) {
            float xn = xs[((t + 4 + j) & (TT - 1)) * UU + u];  // prefetch

            // partial over this half's 16 k's: 4 chains x 4 deep
            float p0 = 0.f, p1 = 0.f, p2 = 0.f, p3 = 0.f;
            #pragma unroll
            for (int k = 0; k < 16; k += 4) {
                float h0 = bperm(pbase + (k + 0) * 4, h);
                float h1 = bperm(pbase + (k + 1) * 4, h);
                float h2 = bperm(pbase + (k + 2) * 4, h);
                float h3 = bperm(pbase + (k + 3) * 4, h);
                p0 = fmaf(h0, wh[k],     p0);
                p1 = fmaf(h1, wh[k + 1], p1);
                p2 = fmaf(h2, wh[k + 2], p2);
                p3 = fmaf(h3, wh[k + 3], p3);
            }
            float ps = (p0 + p1) + (p2 + p3);
            float other = bperm(xaddr, ps);          // other half's partial
            h = fast_tanh((ps + other) + xr[j]);
            xr[j] = xn;
        }
    }

    // ---- fused heads (once; readlane-only — h[u] lives in lane u) ----
    const int jh = L & 15;
    float s = b1[jh];
    #pragma unroll
    for (int k = 0; k < UU; ++k) {
        float hk = rdlane(h, k);
        s = fmaf(hk, W1[k * FF1 + jh], s);
    }
    float z = b2[0];
    #pragma unroll
    for (int jj = 0; jj < FF1; ++jj) {
        float yj = rdlane(s, jj);
        z = fmaf(yj, W2[jj], z);
    }
    if (L == 0) {
        float e = __builtin_amdgcn_exp2f(-z * 1.4426950408889634f); // e^{-z}
        out[b] = __builtin_amdgcn_rcpf(1.0f + e);
    }
}

// ---------------------------------------------------------------------------
extern "C" void kernel_launch(void* const* d_in, const int* in_sizes, int n_in,
                              void* d_out, int out_size, void* d_ws, size_t ws_size,
                              hipStream_t stream) {
    const int*   tokens = (const int*)  d_in[0];
    const float* emb    = (const float*)d_in[1];
    const float* Wx     = (const float*)d_in[2];
    const float* Wh     = (const float*)d_in[3];
    const float* bias   = (const float*)d_in[4];
    const float* W1     = (const float*)d_in[5];
    const float* b1     = (const float*)d_in[6];
    const float* W2     = (const float*)d_in[7];
    const float* b2     = (const float*)d_in[8];
    float* out = (float*)d_out;

    const int vocab = in_sizes[1] / EE;        // 50000
    float* P = (float*)d_ws;                   // vocab*32*4 = 6.4 MB

    // A: 16 rows per 64-thread wave -> 3125 blocks (~12 waves/CU)
    proj_gemv<<<dim3(vocab / 16), dim3(64), 0, stream>>>(
        emb, Wx, bias, P, vocab);

    // B: 1 batch row per wave -> 512 blocks x 64 threads (2 blocks/CU)
    scan_heads<<<dim3(BB), dim3(64), 0, stream>>>(
        tokens, P, Wh, W1, b1, W2, b2, out);
}